// Round 11
// baseline (972.767 us; speedup 1.0000x reference)
//
#include <hip/hip_runtime.h>
#include <math.h>

// B=8, L=8192, W=128, MODES=32, NL=4, SEG=4 (seglen 2048), CM=8, H1=128

// ---------------- workspace layout (in floats) ----------------
#define OFF_COSTAB 0
#define OFF_SINTAB 8192
#define OFF_BASTC  16384                     // [32][8192]  cos(2*pi*k*l/L)
#define OFF_BASTS  (OFF_BASTC + 262144)      // [32][8192]  sin  (contiguous -> [64][8192])
#define OFF_UNUSED (OFF_BASTS + 262144)
#define OFF_WBAR   (OFF_UNUSED + 65536)      // [NL][SEG][CM][W]
#define OFF_HFP    (OFF_WBAR + 16384)        // (unused now)
#define OFF_HF     (OFF_HFP + 1048576)       // [1024][64]
#define OFF_CH     (OFF_HF + 65536)          // (unused now; rec fused)
#define OFF_REC    (OFF_CH + 32768)          // [8*128][4]
#define OFF_OMCT   (OFF_REC + 4096)          // [8][32 k][128 o]
#define OFF_OMST   (OFF_OMCT + 32768)        // [8][32 k][128 o]
#define OFF_CG     (OFF_OMST + 32768)        // [8][4][128]
#define OFF_MNMX   (OFF_CG + 4096)           // 8 uints
#define OFF_H      (OFF_MNMX + 16)           // [8][128][8192]

__device__ __forceinline__ unsigned int enc_f(float f) {
    unsigned int u = __float_as_uint(f);
    return (u & 0x80000000u) ? ~u : (u | 0x80000000u);
}
__device__ __forceinline__ float dec_f(unsigned int u) {
    return (u & 0x80000000u) ? __uint_as_float(u ^ 0x80000000u) : __uint_as_float(~u);
}
__device__ __forceinline__ float gelu_f(float x) {
    return 0.5f * x * (1.0f + erff(x * 0.70710678118654752f));
}
__device__ __forceinline__ float sigmoid_f(float x) {
    return 1.0f / (1.0f + expf(-x));
}

// cos/sin(2*pi*m/32) compile-time tables (fold to literals in unrolled FMAs)
constexpr float C32T[32] = {
    1.0f,          0.980785280f,  0.923879533f,  0.831469612f,
    0.707106781f,  0.555570233f,  0.382683432f,  0.195090322f,
    0.0f,         -0.195090322f, -0.382683432f, -0.555570233f,
   -0.707106781f, -0.831469612f, -0.923879533f, -0.980785280f,
   -1.0f,         -0.980785280f, -0.923879533f, -0.831469612f,
   -0.707106781f, -0.555570233f, -0.382683432f, -0.195090322f,
    0.0f,          0.195090322f,  0.382683432f,  0.555570233f,
    0.707106781f,  0.831469612f,  0.923879533f,  0.980785280f};
constexpr float S32T[32] = {
    0.0f,          0.195090322f,  0.382683432f,  0.555570233f,
    0.707106781f,  0.831469612f,  0.923879533f,  0.980785280f,
    1.0f,          0.980785280f,  0.923879533f,  0.831469612f,
    0.707106781f,  0.555570233f,  0.382683432f,  0.195090322f,
    0.0f,         -0.195090322f, -0.382683432f, -0.555570233f,
   -0.707106781f, -0.831469612f, -0.923879533f, -0.980785280f,
   -1.0f,         -0.980785280f, -0.923879533f, -0.831469612f,
   -0.707106781f, -0.555570233f, -0.382683432f, -0.195090322f};

// Butterfly reduce-scatter: exchange half the VALUE SET per level instead of reducing
// every value over all lanes. 32 values over a wave = 31 shfl (vs 32*6=192).
// After all levels lane l holds value rev5(l&31) summed over its 32-lane half.
template<int NV, int M>
__device__ __forceinline__ void bfly_level(float* v, int lane) {
    #pragma unroll
    for (int i = 0; i < NV / 2; i++) {
        bool shi = (lane & M) != 0;
        float snd = shi ? v[i] : v[NV / 2 + i];
        float rcv = __shfl_xor(snd, M);
        v[i] = (shi ? v[NV / 2 + i] : v[i]) + rcv;
    }
}
__device__ __forceinline__ float bfly32_reduce(float* v, int lane) {
    bfly_level<32, 1>(v, lane);
    bfly_level<16, 2>(v, lane);
    bfly_level<8, 4>(v, lane);
    bfly_level<4, 8>(v, lane);
    bfly_level<2, 16>(v, lane);
    return v[0] + __shfl_xor(v[0], 32);   // full 64-lane sum of value rev5(lane&31)
}

// ---------------- init ----------------
__global__ void k_tab(float* ws) {
    int m = blockIdx.x * 256 + threadIdx.x;
    if (m < 8192) {
        double a = (double)m * (6.283185307179586476925286766559 / 8192.0);
        ws[OFF_COSTAB + m] = (float)cos(a);
        ws[OFF_SINTAB + m] = (float)sin(a);
    }
}

__global__ void k_init2(float* ws, const float* __restrict__ cheb_w) {
    int tid = blockIdx.x * 256 + threadIdx.x;
    if (tid < 524288) {
        int j = tid >> 13, l = tid & 8191;
        int k = j & 31;
        int tab = (j < 32) ? OFF_COSTAB : OFF_SINTAB;
        ws[OFF_BASTC + tid] = ws[tab + ((k * l) & 8191)];
    } else if (tid < 524288 + 16384) {
        int r = tid - 524288;           // ((layer*4+s)*8+m)*128 + c
        int c = r & 127;
        int smi = r >> 7;
        const float* wp = cheb_w + ((long)smi * 128 + c) * 128;
        float s = 0.0f;
        for (int o = 0; o < 128; o++) s += wp[o];
        ws[OFF_WBAR + r] = s * (1.0f / 128.0f);
    } else if (tid < 524288 + 16384 + 8) {
        int r = tid - (524288 + 16384);
        unsigned int* mm = (unsigned int*)(ws + OFF_MNMX);
        mm[r] = (r < 4) ? 0xFFFFFFFFu : 0u;
    }
}

// ---------------- fc0 + seg min/max ----------------
__global__ __launch_bounds__(256) void k_fc0(float* ws, const float* __restrict__ x,
                                             const float* __restrict__ w,
                                             const float* __restrict__ bias) {
    int bid = blockIdx.x;
    int b = bid >> 5;
    int l0 = (bid & 31) * 256;
    int t = threadIdx.x;
    int l = l0 + t;
    float x0 = x[((long)b * 8192 + l) * 2];
    float x1 = x[((long)b * 8192 + l) * 2 + 1];
    float* hb = ws + OFF_H + (long)b * 128 * 8192;
    float mn = 1e30f, mx = -1e30f;
    for (int c = 0; c < 128; c++) {
        float v = fmaf(x0, w[c], fmaf(x1, w[128 + c], bias[c]));
        hb[(long)c * 8192 + l] = v;
        mn = fminf(mn, v); mx = fmaxf(mx, v);
    }
    for (int off = 32; off; off >>= 1) {
        mn = fminf(mn, __shfl_down(mn, off));
        mx = fmaxf(mx, __shfl_down(mx, off));
    }
    __shared__ float rmn[4], rmx[4];
    if ((t & 63) == 0) { rmn[t >> 6] = mn; rmx[t >> 6] = mx; }
    __syncthreads();
    if (t == 0) {
        for (int w2 = 1; w2 < 4; w2++) { mn = fminf(mn, rmn[w2]); mx = fmaxf(mx, rmx[w2]); }
        unsigned int* mm = (unsigned int*)(ws + OFF_MNMX);
        int seg = l0 >> 11;
        atomicMin(&mm[seg], enc_f(mn));
        atomicMax(&mm[4 + seg], enc_f(mx));
    }
}

// ---------------- fused DFT(32 modes) + Chebyshev coeffs + rec ----------------
__global__ __launch_bounds__(256, 3) void k_dftcb(float* ws, int layer) {
    int row = blockIdx.x;              // b*128 + c
    int t = threadIdx.x;               // r = 0..255
    int lane = t & 63;
    const float* hr = ws + OFF_H + (long)row * 8192;
    __shared__ float red[4][96];
    int wv = t >> 6;
    int vid = ((lane & 1) << 4) | ((lane & 2) << 2) | (lane & 4) |
              ((lane & 8) >> 2) | ((lane & 16) >> 4);   // rev5(lane&31)

    float ha[32];
    #pragma unroll
    for (int a = 0; a < 32; a++) ha[a] = hr[a * 256 + t];

    // ---- Chebyshev coefficients: accumulate ch[32] = (s*8+m), butterfly once ----
    const unsigned int* mm = (const unsigned int*)(ws + OFF_MNMX);
    float ch[32];
    #pragma unroll
    for (int i = 0; i < 32; i++) ch[i] = 0.0f;
    #pragma unroll
    for (int s = 0; s < 4; s++) {
        float mn = dec_f(mm[s]), mx = dec_f(mm[4 + s]);
        float sc = 2.0f / (mx - mn);
        #pragma unroll
        for (int e = 0; e < 8; e++) {
            float xn = (ha[s * 8 + e] - mn) * sc - 1.0f;
            float tpp = 1.0f, tp = xn;
            ch[s * 8 + 0] += xn;
            ch[s * 8 + 1] += xn * xn;
            #pragma unroll
            for (int mI = 2; mI < 8; mI++) {
                float tn = 2.0f * xn * tp - tpp;
                ch[s * 8 + mI] += xn * tn;
                tpp = tp; tp = tn;
            }
        }
    }
    {
        float cv = bfly32_reduce(ch, lane);
        if (lane < 32) red[wv][64 + vid] = cv;
    }

    // ---- inner 32-point real DFT over a, folded a<->32-a ----
    float ep[16], em[16];
    #pragma unroll
    for (int a = 1; a < 16; a++) { ep[a] = ha[a] + ha[32 - a]; em[a] = ha[a] - ha[32 - a]; }
    float h0 = ha[0], h16 = ha[16];
    float Ca[17], Sa[17];
    #pragma unroll
    for (int k = 0; k <= 16; k++) {
        float ca = (k & 1) ? (h0 - h16) : (h0 + h16);
        float sa = 0.0f;
        #pragma unroll
        for (int a = 1; a < 16; a++) {
            ca = fmaf(ep[a], C32T[(k * a) & 31], ca);
            sa = fmaf(em[a], S32T[(k * a) & 31], sa);
        }
        Ca[k] = ca; Sa[k] = sa;
    }
    // Hermitian: Ca[32-k]=Ca[k], Sa[32-k]=-Sa[k]

    // ---- twiddle by theta = 2*pi*k*t/8192 into xr[32], xi[32]; butterfly each ----
    const float* ct = ws + OFF_COSTAB;
    const float* st = ws + OFF_SINTAB;
    float xr[32], xi[32];
    #pragma unroll
    for (int k = 0; k < 32; k++) {
        float caf = (k <= 16) ? Ca[k] : Ca[32 - k];
        float saf = (k <= 16) ? Sa[k] : -Sa[32 - k];
        float c = ct[(k * t) & 8191];
        float s = st[(k * t) & 8191];
        xr[k] = caf * c - saf * s;               // partial of sum h*cos
        xi[k] = fmaf(saf, c, caf * s);           // partial of sum h*sin
    }
    {
        float rv = bfly32_reduce(xr, lane);
        if (lane < 32) red[wv][vid] = rv;
    }
    {
        float iv = bfly32_reduce(xi, lane);
        if (lane < 32) red[wv][32 + vid] = iv;
    }
    __syncthreads();
    if (t < 96) {
        float s4 = red[0][t] + red[1][t] + red[2][t] + red[3][t];
        if (t < 64) {
            ws[OFF_HF + (long)row * 64 + t] = s4;    // [k]=cos-sum, [32+k]=sin-sum
        } else {
            red[0][t] = s4 * (1.0f / 2048.0f);       // scaled Cheb coeff, kept in LDS
        }
    }
    __syncthreads();
    // ---- rec = tanh(C . wbar) (fused k_b1) ----
    if (t < 4) {
        const float* wb = ws + OFF_WBAR + ((layer * 4 + t) * 8) * 128 + (row & 127);
        float a = 0.0f;
        #pragma unroll
        for (int mI = 0; mI < 8; mI++) a = fmaf(red[0][64 + t * 8 + mI], wb[mI * 128], a);
        ws[OFF_REC + (long)row * 4 + t] = tanhf(a);
    }
}

// ---------------- B2: mode mix -> omT (k-major); cgate; reset minmax ----------------
__global__ void k_b2(float* ws, const float* __restrict__ swr, const float* __restrict__ swi,
                     const float* __restrict__ gw, const float* __restrict__ gb, int layer) {
    int tid = blockIdx.x * 256 + threadIdx.x;
    if (tid < 32768) {
        int b = tid >> 12, o = (tid >> 5) & 127, k = tid & 31;
        const float* hfb = ws + OFF_HF + (long)b * 8192;  // [128][64]
        const float* wr = swr + (long)layer * 524288 + (long)o * 32 + k;
        const float* wi = swi + (long)layer * 524288 + (long)o * 32 + k;
        float omr = 0.0f, omi = 0.0f;
        for (int i = 0; i < 128; i++) {
            float hr = hfb[i * 64 + k];
            float hs = hfb[i * 64 + 32 + k];
            float wrv = wr[(long)i * 4096], wiv = wi[(long)i * 4096];
            omr = fmaf(hr, wrv, fmaf(hs, wiv, omr));
            omi = fmaf(hr, wiv, fmaf(-hs, wrv, omi));
        }
        float ck = (k == 0) ? (1.0f / 8192.0f) : (2.0f / 8192.0f);
        ws[OFF_OMCT + ((long)b * 32 + k) * 128 + o] = ck * omr;
        ws[OFF_OMST + ((long)b * 32 + k) * 128 + o] = -ck * omi;
    } else if (tid < 32768 + 4096) {
        int r = tid - 32768;
        int b = r >> 9, s = (r >> 7) & 3, o = r & 127;
        float a = gb[layer * 128 + o];
        const float* recp = ws + OFF_REC + (long)b * 512 + s;
        const float* g2 = gw + (long)layer * 32768 + 16384 + o;
        for (int c = 0; c < 128; c++) a = fmaf(recp[c * 4], g2[c * 128], a);
        ws[OFF_CG + (long)(b * 4 + s) * 128 + o] = a;
    }
    if (blockIdx.x == gridDim.x - 1 && threadIdx.x < 8) {
        unsigned int* mm = (unsigned int*)(ws + OFF_MNMX);
        mm[threadIdx.x] = (threadIdx.x < 4) ? 0xFFFFFFFFu : 0u;
    }
}

// ---------------- fused layer: irfft + conv + gelu + gate + update (in place) ----------------
// r5/r10 geometry; weights now loaded as WAVE-UNIFORM VECTOR broadcasts (no readfirstlane
// on the weight base -> global_load_dwordx4, one line per wave): weight traffic moves from
// SMEM/lgkmcnt to VMEM/vmcnt, so lgkm carries only in-order DS and the compiler no longer
// needs lgkmcnt(0) full drains before every FMA batch (SMEM is out-of-order, DS in-order;
// mixing them forced coarse drains -- the measured 42% VALU-idle).
__global__ __launch_bounds__(512, 4) void k_fuse(
    float* __restrict__ hglob,            // ws + OFF_H
    const float* __restrict__ basc,       // ws + OFF_BASTC
    const float* __restrict__ bass,       // ws + OFF_BASTS
    const float* __restrict__ omct,       // ws + OFF_OMCT
    const float* __restrict__ omst,       // ws + OFF_OMST
    const float* __restrict__ rec,        // ws + OFF_REC
    const float* __restrict__ cgt,        // ws + OFF_CG
    unsigned int* __restrict__ mnmx,      // ws + OFF_MNMX
    const float* __restrict__ cw, const float* __restrict__ cb,
    const float* __restrict__ gw, int layer) {
    __shared__ float hx[128 * 128];
    __shared__ float rmn[8], rmx[8];
    int bid = blockIdx.x;                  // 512 blocks
    int b = bid >> 6;
    int l0 = (bid & 63) * 128;
    int seg = l0 >> 11;
    int t = threadIdx.x;
    float* hb = hglob + (long)b * 1048576;

    // stage h tile [128 ch][128 pos]
    #pragma unroll
    for (int i = 0; i < 8; i++) {
        int idx = t + i * 512;
        int row = idx >> 5, c4 = (idx & 31) * 4;
        *(float4*)&hx[row * 128 + c4] = *(const float4*)&hb[(long)row * 8192 + l0 + c4];
    }
    __syncthreads();

    int p = t & 63;                 // lane = position (and p+64)
    int c0 = (t >> 6) * 16;         // wave's channel base -- NOT readfirstlane'd:
                                    // divergence analysis can't prove uniform -> weight
                                    // loads become VMEM broadcasts (vmcnt, not lgkm)

    float acc0[16] = {}, acc1[16] = {};

    // ---- inverse DFT (32 modes): 4 lane loads + 8 broadcast float4 weights per k ----
    const float* btp = basc + l0 + p;
    const float* bsp = bass + l0 + p;
    const float* omc = omct + (long)b * 4096 + c0;
    const float* oms = omst + (long)b * 4096 + c0;
    #pragma unroll 2
    for (int k = 0; k < 32; k++) {
        float bc0 = btp[k * 8192];
        float bc1 = btp[k * 8192 + 64];
        float bs0 = bsp[k * 8192];
        float bs1 = bsp[k * 8192 + 64];
        float wc[16], wsn[16];
        *(float4*)&wc[0]   = *(const float4*)&omc[k * 128];
        *(float4*)&wc[4]   = *(const float4*)&omc[k * 128 + 4];
        *(float4*)&wc[8]   = *(const float4*)&omc[k * 128 + 8];
        *(float4*)&wc[12]  = *(const float4*)&omc[k * 128 + 12];
        *(float4*)&wsn[0]  = *(const float4*)&oms[k * 128];
        *(float4*)&wsn[4]  = *(const float4*)&oms[k * 128 + 4];
        *(float4*)&wsn[8]  = *(const float4*)&oms[k * 128 + 8];
        *(float4*)&wsn[12] = *(const float4*)&oms[k * 128 + 12];
        #pragma unroll
        for (int c = 0; c < 16; c++) {
            acc0[c] = fmaf(wc[c], bc0, fmaf(wsn[c], bs0, acc0[c]));
            acc1[c] = fmaf(wc[c], bc1, fmaf(wsn[c], bs1, acc1[c]));
        }
    }
    // ---- 1x1 conv bypass: 2 ds_reads + 4 broadcast float4 weights per j ----
    const float* cwt = cw + (long)layer * 16384 + c0;
    #pragma unroll 2
    for (int j = 0; j < 128; j++) {
        float hv0 = hx[j * 128 + p];
        float hv1 = hx[j * 128 + 64 + p];
        float wv[16];
        *(float4*)&wv[0]  = *(const float4*)&cwt[j * 128];
        *(float4*)&wv[4]  = *(const float4*)&cwt[j * 128 + 4];
        *(float4*)&wv[8]  = *(const float4*)&cwt[j * 128 + 8];
        *(float4*)&wv[12] = *(const float4*)&cwt[j * 128 + 12];
        #pragma unroll
        for (int c = 0; c < 16; c++) {
            acc0[c] = fmaf(wv[c], hv0, acc0[c]);
            acc1[c] = fmaf(wv[c], hv1, acc1[c]);
        }
    }
    // bias + gelu -> x_fno kept in regs
    const float* cbl = cb + layer * 128 + c0;
    #pragma unroll
    for (int c = 0; c < 16; c++) {
        acc0[c] = gelu_f(acc0[c] + cbl[c]);
        acc1[c] = gelu_f(acc1[c] + cbl[c]);
    }
    __syncthreads();   // all conv reads of h done
    #pragma unroll
    for (int c = 0; c < 16; c++) {
        hx[(c0 + c) * 128 + p] = acc0[c];
        hx[(c0 + c) * 128 + 64 + p] = acc1[c];
    }
    __syncthreads();

    // ---- gate GEMM over x_fno: same broadcast-weight structure ----
    const float* gwl = gw + (long)layer * 32768 + c0;
    float gac0[16] = {}, gac1[16] = {};
    #pragma unroll 2
    for (int j = 0; j < 128; j++) {
        float xv0 = hx[j * 128 + p];
        float xv1 = hx[j * 128 + 64 + p];
        float wv[16];
        *(float4*)&wv[0]  = *(const float4*)&gwl[j * 128];
        *(float4*)&wv[4]  = *(const float4*)&gwl[j * 128 + 4];
        *(float4*)&wv[8]  = *(const float4*)&gwl[j * 128 + 8];
        *(float4*)&wv[12] = *(const float4*)&gwl[j * 128 + 12];
        #pragma unroll
        for (int c = 0; c < 16; c++) {
            gac0[c] = fmaf(wv[c], xv0, gac0[c]);
            gac1[c] = fmaf(wv[c], xv1, gac1[c]);
        }
    }
    // epilogue: sigmoid gate, h update, seg min/max
    const float* cgp = cgt + (long)(b * 4 + seg) * 128 + c0;
    const float* rcp = rec + (long)(b * 128 + c0) * 4 + seg;
    float mnv = 1e30f, mxv = -1e30f;
    #pragma unroll
    for (int c = 0; c < 16; c++) {
        float cgv = cgp[c];
        float rv = rcp[c * 4];
        float g0 = sigmoid_f(gac0[c] + cgv);
        float g1 = sigmoid_f(gac1[c] + cgv);
        float v0 = fmaf(g0, rv, acc0[c]);
        float v1 = fmaf(g1, rv, acc1[c]);
        mnv = fminf(mnv, fminf(v0, v1));
        mxv = fmaxf(mxv, fmaxf(v0, v1));
        hb[(long)(c0 + c) * 8192 + l0 + p] = v0;
        hb[(long)(c0 + c) * 8192 + l0 + 64 + p] = v1;
    }
    for (int off = 32; off; off >>= 1) {
        mnv = fminf(mnv, __shfl_down(mnv, off));
        mxv = fmaxf(mxv, __shfl_down(mxv, off));
    }
    if ((t & 63) == 0) { rmn[t >> 6] = mnv; rmx[t >> 6] = mxv; }
    __syncthreads();
    if (t == 0) {
        for (int w2 = 1; w2 < 8; w2++) { mnv = fminf(mnv, rmn[w2]); mxv = fmaxf(mxv, rmx[w2]); }
        atomicMin(&mnmx[seg], enc_f(mnv));
        atomicMax(&mnmx[4 + seg], enc_f(mxv));
    }
}

// ---------------- final fc1(gelu) + fc2: same broadcast-weight structure ----------------
__global__ __launch_bounds__(512, 4) void k_fc12(
    const float* __restrict__ hglob, const float* __restrict__ f1w,
    const float* __restrict__ f1b, const float* __restrict__ f2w,
    const float* __restrict__ f2b, float* __restrict__ out) {
    __shared__ float hx[128 * 128];
    int bid = blockIdx.x;                  // 512 blocks
    int b = bid >> 6;
    int l0 = (bid & 63) * 128;
    int t = threadIdx.x;
    const float* hb = hglob + (long)b * 1048576;
    #pragma unroll
    for (int i = 0; i < 8; i++) {
        int idx = t + i * 512;
        int row = idx >> 5, c4 = (idx & 31) * 4;
        *(float4*)&hx[row * 128 + c4] = *(const float4*)&hb[(long)row * 8192 + l0 + c4];
    }
    __syncthreads();
    int p = t & 63;
    int h0 = (t >> 6) * 16;         // not readfirstlane'd: weight loads -> VMEM broadcast
    float acc0[16] = {}, acc1[16] = {};
    const float* f1 = f1w + h0;
    #pragma unroll 2
    for (int j = 0; j < 128; j++) {
        float xv0 = hx[j * 128 + p];
        float xv1 = hx[j * 128 + 64 + p];
        float wv[16];
        *(float4*)&wv[0]  = *(const float4*)&f1[j * 128];
        *(float4*)&wv[4]  = *(const float4*)&f1[j * 128 + 4];
        *(float4*)&wv[8]  = *(const float4*)&f1[j * 128 + 8];
        *(float4*)&wv[12] = *(const float4*)&f1[j * 128 + 12];
        #pragma unroll
        for (int c = 0; c < 16; c++) {
            acc0[c] = fmaf(wv[c], xv0, acc0[c]);
            acc1[c] = fmaf(wv[c], xv1, acc1[c]);
        }
    }
    float outp0 = 0.0f, outp1 = 0.0f;
    #pragma unroll
    for (int c = 0; c < 16; c++) {
        float bias = f1b[h0 + c];
        float fw = f2w[h0 + c];
        outp0 = fmaf(fw, gelu_f(acc0[c] + bias), outp0);
        outp1 = fmaf(fw, gelu_f(acc1[c] + bias), outp1);
    }
    __syncthreads();   // done reading hx; reuse as wave-partial buffer [8][128]
    hx[(t >> 6) * 128 + p] = outp0;
    hx[(t >> 6) * 128 + 64 + p] = outp1;
    __syncthreads();
    if (t < 128) {
        float s = f2b[0];
        #pragma unroll
        for (int gg = 0; gg < 8; gg++) s += hx[gg * 128 + t];
        out[(long)b * 8192 + l0 + t] = s;
    }
}

extern "C" void kernel_launch(void* const* d_in, const int* in_sizes, int n_in,
                              void* d_out, int out_size, void* d_ws, size_t ws_size,
                              hipStream_t stream) {
    const float* x     = (const float*)d_in[0];
    const float* fc0_w = (const float*)d_in[1];
    const float* fc0_b = (const float*)d_in[2];
    const float* swr   = (const float*)d_in[3];
    const float* swi   = (const float*)d_in[4];
    const float* cw    = (const float*)d_in[5];
    const float* cb    = (const float*)d_in[6];
    const float* chw   = (const float*)d_in[7];
    const float* gw    = (const float*)d_in[8];
    const float* gb    = (const float*)d_in[9];
    const float* f1w   = (const float*)d_in[10];
    const float* f1b   = (const float*)d_in[11];
    const float* f2w   = (const float*)d_in[12];
    const float* f2b   = (const float*)d_in[13];
    float* ws = (float*)d_ws;
    float* out = (float*)d_out;

    k_tab<<<32, 256, 0, stream>>>(ws);
    k_init2<<<2112, 256, 0, stream>>>(ws, chw);
    k_fc0<<<256, 256, 0, stream>>>(ws, x, fc0_w, fc0_b);
    for (int layer = 0; layer < 4; layer++) {
        k_dftcb<<<1024, 256, 0, stream>>>(ws, layer);
        k_b2<<<144, 256, 0, stream>>>(ws, swr, swi, gw, gb, layer);
        k_fuse<<<512, 512, 0, stream>>>(ws + OFF_H, ws + OFF_BASTC, ws + OFF_BASTS,
                                        ws + OFF_OMCT, ws + OFF_OMST, ws + OFF_REC,
                                        ws + OFF_CG, (unsigned int*)(ws + OFF_MNMX),
                                        cw, cb, gw, layer);
    }
    k_fc12<<<512, 512, 0, stream>>>(ws + OFF_H, f1w, f1b, f2w, f2b, out);
}

// Round 12
// 533.745 us; speedup vs baseline: 1.8225x; 1.8225x over previous
//
#include <hip/hip_runtime.h>
#include <math.h>

// B=8, L=8192, W=128, MODES=32, NL=4, SEG=4 (seglen 2048), CM=8, H1=128

// ---------------- workspace layout (in floats) ----------------
#define OFF_COSTAB 0
#define OFF_SINTAB 8192
#define OFF_BASTC  16384                     // [32][8192]  cos(2*pi*k*l/L)
#define OFF_BASTS  (OFF_BASTC + 262144)      // [32][8192]  sin  (contiguous -> [64][8192])
#define OFF_UNUSED (OFF_BASTS + 262144)
#define OFF_WBAR   (OFF_UNUSED + 65536)      // [NL][SEG][CM][W]
#define OFF_HFP    (OFF_WBAR + 16384)        // (unused now)
#define OFF_HF     (OFF_HFP + 1048576)       // [1024][64]
#define OFF_CH     (OFF_HF + 65536)          // (unused now; rec fused)
#define OFF_REC    (OFF_CH + 32768)          // [8*128][4]
#define OFF_OMCT   (OFF_REC + 4096)          // [8][32 k][128 o]
#define OFF_OMST   (OFF_OMCT + 32768)        // [8][32 k][128 o]
#define OFF_CG     (OFF_OMST + 32768)        // [8][4][128]
#define OFF_MNMX   (OFF_CG + 4096)           // 8 uints
#define OFF_H      (OFF_MNMX + 16)           // [8][128][8192]

__device__ __forceinline__ unsigned int enc_f(float f) {
    unsigned int u = __float_as_uint(f);
    return (u & 0x80000000u) ? ~u : (u | 0x80000000u);
}
__device__ __forceinline__ float dec_f(unsigned int u) {
    return (u & 0x80000000u) ? __uint_as_float(u ^ 0x80000000u) : __uint_as_float(~u);
}
__device__ __forceinline__ float gelu_f(float x) {
    return 0.5f * x * (1.0f + erff(x * 0.70710678118654752f));
}
__device__ __forceinline__ float sigmoid_f(float x) {
    return 1.0f / (1.0f + expf(-x));
}

// cos/sin(2*pi*m/32) compile-time tables (fold to literals in unrolled FMAs)
constexpr float C32T[32] = {
    1.0f,          0.980785280f,  0.923879533f,  0.831469612f,
    0.707106781f,  0.555570233f,  0.382683432f,  0.195090322f,
    0.0f,         -0.195090322f, -0.382683432f, -0.555570233f,
   -0.707106781f, -0.831469612f, -0.923879533f, -0.980785280f,
   -1.0f,         -0.980785280f, -0.923879533f, -0.831469612f,
   -0.707106781f, -0.555570233f, -0.382683432f, -0.195090322f,
    0.0f,          0.195090322f,  0.382683432f,  0.555570233f,
    0.707106781f,  0.831469612f,  0.923879533f,  0.980785280f};
constexpr float S32T[32] = {
    0.0f,          0.195090322f,  0.382683432f,  0.555570233f,
    0.707106781f,  0.831469612f,  0.923879533f,  0.980785280f,
    1.0f,          0.980785280f,  0.923879533f,  0.831469612f,
    0.707106781f,  0.555570233f,  0.382683432f,  0.195090322f,
    0.0f,         -0.195090322f, -0.382683432f, -0.555570233f,
   -0.707106781f, -0.831469612f, -0.923879533f, -0.980785280f,
   -1.0f,         -0.980785280f, -0.923879533f, -0.831469612f,
   -0.707106781f, -0.555570233f, -0.382683432f, -0.195090322f};

// Butterfly reduce-scatter: exchange half the VALUE SET per level instead of reducing
// every value over all lanes. 32 values over a wave = 31 shfl (vs 32*6=192).
// After all levels lane l holds value rev5(l&31) summed over its 32-lane half.
template<int NV, int M>
__device__ __forceinline__ void bfly_level(float* v, int lane) {
    #pragma unroll
    for (int i = 0; i < NV / 2; i++) {
        bool shi = (lane & M) != 0;
        float snd = shi ? v[i] : v[NV / 2 + i];
        float rcv = __shfl_xor(snd, M);
        v[i] = (shi ? v[NV / 2 + i] : v[i]) + rcv;
    }
}
__device__ __forceinline__ float bfly32_reduce(float* v, int lane) {
    bfly_level<32, 1>(v, lane);
    bfly_level<16, 2>(v, lane);
    bfly_level<8, 4>(v, lane);
    bfly_level<4, 8>(v, lane);
    bfly_level<2, 16>(v, lane);
    return v[0] + __shfl_xor(v[0], 32);   // full 64-lane sum of value rev5(lane&31)
}

// ---------------- init ----------------
__global__ void k_tab(float* ws) {
    int m = blockIdx.x * 256 + threadIdx.x;
    if (m < 8192) {
        double a = (double)m * (6.283185307179586476925286766559 / 8192.0);
        ws[OFF_COSTAB + m] = (float)cos(a);
        ws[OFF_SINTAB + m] = (float)sin(a);
    }
}

__global__ void k_init2(float* ws, const float* __restrict__ cheb_w) {
    int tid = blockIdx.x * 256 + threadIdx.x;
    if (tid < 524288) {
        int j = tid >> 13, l = tid & 8191;
        int k = j & 31;
        int tab = (j < 32) ? OFF_COSTAB : OFF_SINTAB;
        ws[OFF_BASTC + tid] = ws[tab + ((k * l) & 8191)];
    } else if (tid < 524288 + 16384) {
        int r = tid - 524288;           // ((layer*4+s)*8+m)*128 + c
        int c = r & 127;
        int smi = r >> 7;
        const float* wp = cheb_w + ((long)smi * 128 + c) * 128;
        float s = 0.0f;
        for (int o = 0; o < 128; o++) s += wp[o];
        ws[OFF_WBAR + r] = s * (1.0f / 128.0f);
    } else if (tid < 524288 + 16384 + 8) {
        int r = tid - (524288 + 16384);
        unsigned int* mm = (unsigned int*)(ws + OFF_MNMX);
        mm[r] = (r < 4) ? 0xFFFFFFFFu : 0u;
    }
}

// ---------------- fc0 + seg min/max ----------------
__global__ __launch_bounds__(256) void k_fc0(float* ws, const float* __restrict__ x,
                                             const float* __restrict__ w,
                                             const float* __restrict__ bias) {
    int bid = blockIdx.x;
    int b = bid >> 5;
    int l0 = (bid & 31) * 256;
    int t = threadIdx.x;
    int l = l0 + t;
    float x0 = x[((long)b * 8192 + l) * 2];
    float x1 = x[((long)b * 8192 + l) * 2 + 1];
    float* hb = ws + OFF_H + (long)b * 128 * 8192;
    float mn = 1e30f, mx = -1e30f;
    for (int c = 0; c < 128; c++) {
        float v = fmaf(x0, w[c], fmaf(x1, w[128 + c], bias[c]));
        hb[(long)c * 8192 + l] = v;
        mn = fminf(mn, v); mx = fmaxf(mx, v);
    }
    for (int off = 32; off; off >>= 1) {
        mn = fminf(mn, __shfl_down(mn, off));
        mx = fmaxf(mx, __shfl_down(mx, off));
    }
    __shared__ float rmn[4], rmx[4];
    if ((t & 63) == 0) { rmn[t >> 6] = mn; rmx[t >> 6] = mx; }
    __syncthreads();
    if (t == 0) {
        for (int w2 = 1; w2 < 4; w2++) { mn = fminf(mn, rmn[w2]); mx = fmaxf(mx, rmx[w2]); }
        unsigned int* mm = (unsigned int*)(ws + OFF_MNMX);
        int seg = l0 >> 11;
        atomicMin(&mm[seg], enc_f(mn));
        atomicMax(&mm[4 + seg], enc_f(mx));
    }
}

// ---------------- fused DFT(32 modes) + Chebyshev coeffs + rec ----------------
// Twiddle factors now generated by complex recurrence from (c1,s1)=tab[t] (coalesced)
// instead of 64 scattered table loads per thread (stride k*4B across lanes touched up
// to 64 lines per load -- the dominant non-FMA cost of this kernel).
__global__ __launch_bounds__(256, 3) void k_dftcb(float* ws, int layer) {
    int row = blockIdx.x;              // b*128 + c
    int t = threadIdx.x;               // r = 0..255
    int lane = t & 63;
    const float* hr = ws + OFF_H + (long)row * 8192;
    __shared__ float red[4][96];
    int wv = t >> 6;
    int vid = ((lane & 1) << 4) | ((lane & 2) << 2) | (lane & 4) |
              ((lane & 8) >> 2) | ((lane & 16) >> 4);   // rev5(lane&31)

    float ha[32];
    #pragma unroll
    for (int a = 0; a < 32; a++) ha[a] = hr[a * 256 + t];

    // ---- Chebyshev coefficients: accumulate ch[32] = (s*8+m), butterfly once ----
    const unsigned int* mm = (const unsigned int*)(ws + OFF_MNMX);
    float ch[32];
    #pragma unroll
    for (int i = 0; i < 32; i++) ch[i] = 0.0f;
    #pragma unroll
    for (int s = 0; s < 4; s++) {
        float mn = dec_f(mm[s]), mx = dec_f(mm[4 + s]);
        float sc = 2.0f / (mx - mn);
        #pragma unroll
        for (int e = 0; e < 8; e++) {
            float xn = (ha[s * 8 + e] - mn) * sc - 1.0f;
            float tpp = 1.0f, tp = xn;
            ch[s * 8 + 0] += xn;
            ch[s * 8 + 1] += xn * xn;
            #pragma unroll
            for (int mI = 2; mI < 8; mI++) {
                float tn = 2.0f * xn * tp - tpp;
                ch[s * 8 + mI] += xn * tn;
                tpp = tp; tp = tn;
            }
        }
    }
    {
        float cv = bfly32_reduce(ch, lane);
        if (lane < 32) red[wv][64 + vid] = cv;
    }

    // ---- inner 32-point real DFT over a, folded a<->32-a ----
    float ep[16], em[16];
    #pragma unroll
    for (int a = 1; a < 16; a++) { ep[a] = ha[a] + ha[32 - a]; em[a] = ha[a] - ha[32 - a]; }
    float h0 = ha[0], h16 = ha[16];
    float Ca[17], Sa[17];
    #pragma unroll
    for (int k = 0; k <= 16; k++) {
        float ca = (k & 1) ? (h0 - h16) : (h0 + h16);
        float sa = 0.0f;
        #pragma unroll
        for (int a = 1; a < 16; a++) {
            ca = fmaf(ep[a], C32T[(k * a) & 31], ca);
            sa = fmaf(em[a], S32T[(k * a) & 31], sa);
        }
        Ca[k] = ca; Sa[k] = sa;
    }
    // Hermitian: Ca[32-k]=Ca[k], Sa[32-k]=-Sa[k]

    // ---- twiddle theta = 2*pi*k*t/8192 via recurrence; butterfly xr/xi ----
    float c1 = ws[OFF_COSTAB + t];    // coalesced: lane index == t
    float s1 = ws[OFF_SINTAB + t];
    float xr[32], xi[32];
    float ck = 1.0f, sk = 0.0f;       // k = 0
    #pragma unroll
    for (int k = 0; k < 32; k++) {
        float caf = (k <= 16) ? Ca[k] : Ca[32 - k];
        float saf = (k <= 16) ? Sa[k] : -Sa[32 - k];
        xr[k] = caf * ck - saf * sk;              // partial of sum h*cos
        xi[k] = fmaf(saf, ck, caf * sk);          // partial of sum h*sin
        float cn = fmaf(ck, c1, -sk * s1);        // advance twiddle by theta_1
        float sn = fmaf(sk, c1, ck * s1);
        ck = cn; sk = sn;
    }
    {
        float rv = bfly32_reduce(xr, lane);
        if (lane < 32) red[wv][vid] = rv;
    }
    {
        float iv = bfly32_reduce(xi, lane);
        if (lane < 32) red[wv][32 + vid] = iv;
    }
    __syncthreads();
    if (t < 96) {
        float s4 = red[0][t] + red[1][t] + red[2][t] + red[3][t];
        if (t < 64) {
            ws[OFF_HF + (long)row * 64 + t] = s4;    // [k]=cos-sum, [32+k]=sin-sum
        } else {
            red[0][t] = s4 * (1.0f / 2048.0f);       // scaled Cheb coeff, kept in LDS
        }
    }
    __syncthreads();
    // ---- rec = tanh(C . wbar) (fused k_b1) ----
    if (t < 4) {
        const float* wb = ws + OFF_WBAR + ((layer * 4 + t) * 8) * 128 + (row & 127);
        float a = 0.0f;
        #pragma unroll
        for (int mI = 0; mI < 8; mI++) a = fmaf(red[0][64 + t * 8 + mI], wb[mI * 128], a);
        ws[OFF_REC + (long)row * 4 + t] = tanhf(a);
    }
}

// ---------------- B2: mode mix -> omT (k-major); cgate; reset minmax ----------------
__global__ void k_b2(float* ws, const float* __restrict__ swr, const float* __restrict__ swi,
                     const float* __restrict__ gw, const float* __restrict__ gb, int layer) {
    int tid = blockIdx.x * 256 + threadIdx.x;
    if (tid < 32768) {
        int b = tid >> 12, o = (tid >> 5) & 127, k = tid & 31;
        const float* hfb = ws + OFF_HF + (long)b * 8192;  // [128][64]
        const float* wr = swr + (long)layer * 524288 + (long)o * 32 + k;
        const float* wi = swi + (long)layer * 524288 + (long)o * 32 + k;
        float omr = 0.0f, omi = 0.0f;
        for (int i = 0; i < 128; i++) {
            float hr = hfb[i * 64 + k];
            float hs = hfb[i * 64 + 32 + k];
            float wrv = wr[(long)i * 4096], wiv = wi[(long)i * 4096];
            omr = fmaf(hr, wrv, fmaf(hs, wiv, omr));
            omi = fmaf(hr, wiv, fmaf(-hs, wrv, omi));
        }
        float ck = (k == 0) ? (1.0f / 8192.0f) : (2.0f / 8192.0f);
        ws[OFF_OMCT + ((long)b * 32 + k) * 128 + o] = ck * omr;
        ws[OFF_OMST + ((long)b * 32 + k) * 128 + o] = -ck * omi;
    } else if (tid < 32768 + 4096) {
        int r = tid - 32768;
        int b = r >> 9, s = (r >> 7) & 3, o = r & 127;
        float a = gb[layer * 128 + o];
        const float* recp = ws + OFF_REC + (long)b * 512 + s;
        const float* g2 = gw + (long)layer * 32768 + 16384 + o;
        for (int c = 0; c < 128; c++) a = fmaf(recp[c * 4], g2[c * 128], a);
        ws[OFF_CG + (long)(b * 4 + s) * 128 + o] = a;
    }
    if (blockIdx.x == gridDim.x - 1 && threadIdx.x < 8) {
        unsigned int* mm = (unsigned int*)(ws + OFF_MNMX);
        mm[threadIdx.x] = (threadIdx.x < 4) ? 0xFFFFFFFFu : 0u;
    }
}

// ---------------- fused layer: irfft + conv + gelu + gate + update (in place) ----------------
// r5/r10 structure (proven ~85us): 2 position-tiles per block (128 pos), wave-uniform scalar
// weights, 16 ch/wave, LDS 64KB -> 2 blocks/CU. Do not perturb: occupancy up (r6), LDS
// staging (r7/r8), VMEM broadcast (r11) all regress; unroll depth neutral (r9).
__global__ __launch_bounds__(512, 4) void k_fuse(
    float* __restrict__ hglob,            // ws + OFF_H
    const float* __restrict__ basc,       // ws + OFF_BASTC
    const float* __restrict__ bass,       // ws + OFF_BASTS
    const float* __restrict__ omct,       // ws + OFF_OMCT
    const float* __restrict__ omst,       // ws + OFF_OMST
    const float* __restrict__ rec,        // ws + OFF_REC
    const float* __restrict__ cgt,        // ws + OFF_CG
    unsigned int* __restrict__ mnmx,      // ws + OFF_MNMX
    const float* __restrict__ cw, const float* __restrict__ cb,
    const float* __restrict__ gw, int layer) {
    __shared__ float hx[128 * 128];
    __shared__ float rmn[8], rmx[8];
    int bid = blockIdx.x;                  // 512 blocks
    int b = bid >> 6;
    int l0 = (bid & 63) * 128;
    int seg = l0 >> 11;
    int t = threadIdx.x;
    float* hb = hglob + (long)b * 1048576;

    // stage h tile [128 ch][128 pos]
    #pragma unroll
    for (int i = 0; i < 8; i++) {
        int idx = t + i * 512;
        int row = idx >> 5, c4 = (idx & 31) * 4;
        *(float4*)&hx[row * 128 + c4] = *(const float4*)&hb[(long)row * 8192 + l0 + c4];
    }
    __syncthreads();

    int p = t & 63;                                         // lane = position (and p+64)
    int c0 = __builtin_amdgcn_readfirstlane((t >> 6) * 16); // wave's channel base

    float acc0[16] = {}, acc1[16] = {};

    // ---- inverse DFT (32 modes): 4 coalesced lane loads + 32 scalar weights per k ----
    const float* btp = basc + l0 + p;
    const float* bsp = bass + l0 + p;
    const float* omc = omct + (long)b * 4096 + c0;
    const float* oms = omst + (long)b * 4096 + c0;
    #pragma unroll 4
    for (int k = 0; k < 32; k++) {
        float bc0 = btp[k * 8192];
        float bc1 = btp[k * 8192 + 64];
        float bs0 = bsp[k * 8192];
        float bs1 = bsp[k * 8192 + 64];
        #pragma unroll
        for (int c = 0; c < 16; c++) {
            float wc = omc[k * 128 + c], wsn = oms[k * 128 + c];
            acc0[c] = fmaf(wc, bc0, fmaf(wsn, bs0, acc0[c]));
            acc1[c] = fmaf(wc, bc1, fmaf(wsn, bs1, acc1[c]));
        }
    }
    // ---- 1x1 conv bypass: 2 conflict-free ds_reads + 16 scalar weights per j ----
    const float* cwt = cw + (long)layer * 16384 + c0;
    #pragma unroll 4
    for (int j = 0; j < 128; j++) {
        float hv0 = hx[j * 128 + p];
        float hv1 = hx[j * 128 + 64 + p];
        #pragma unroll
        for (int c = 0; c < 16; c++) {
            float wv = cwt[j * 128 + c];
            acc0[c] = fmaf(wv, hv0, acc0[c]);
            acc1[c] = fmaf(wv, hv1, acc1[c]);
        }
    }
    // bias + gelu -> x_fno kept in regs
    const float* cbl = cb + layer * 128 + c0;
    #pragma unroll
    for (int c = 0; c < 16; c++) {
        acc0[c] = gelu_f(acc0[c] + cbl[c]);
        acc1[c] = gelu_f(acc1[c] + cbl[c]);
    }
    __syncthreads();   // all conv reads of h done
    #pragma unroll
    for (int c = 0; c < 16; c++) {
        hx[(c0 + c) * 128 + p] = acc0[c];
        hx[(c0 + c) * 128 + 64 + p] = acc1[c];
    }
    __syncthreads();

    // ---- gate GEMM over x_fno: same scalar-weight structure ----
    const float* gwl = gw + (long)layer * 32768 + c0;
    float gac0[16] = {}, gac1[16] = {};
    #pragma unroll 4
    for (int j = 0; j < 128; j++) {
        float xv0 = hx[j * 128 + p];
        float xv1 = hx[j * 128 + 64 + p];
        #pragma unroll
        for (int c = 0; c < 16; c++) {
            float wv = gwl[j * 128 + c];
            gac0[c] = fmaf(wv, xv0, gac0[c]);
            gac1[c] = fmaf(wv, xv1, gac1[c]);
        }
    }
    // epilogue: sigmoid gate, h update, seg min/max
    const float* cgp = cgt + (long)(b * 4 + seg) * 128 + c0;
    const float* rcp = rec + (long)(b * 128 + c0) * 4 + seg;
    float mnv = 1e30f, mxv = -1e30f;
    #pragma unroll
    for (int c = 0; c < 16; c++) {
        float cgv = cgp[c];
        float rv = rcp[c * 4];
        float g0 = sigmoid_f(gac0[c] + cgv);
        float g1 = sigmoid_f(gac1[c] + cgv);
        float v0 = fmaf(g0, rv, acc0[c]);
        float v1 = fmaf(g1, rv, acc1[c]);
        mnv = fminf(mnv, fminf(v0, v1));
        mxv = fmaxf(mxv, fmaxf(v0, v1));
        hb[(long)(c0 + c) * 8192 + l0 + p] = v0;
        hb[(long)(c0 + c) * 8192 + l0 + 64 + p] = v1;
    }
    for (int off = 32; off; off >>= 1) {
        mnv = fminf(mnv, __shfl_down(mnv, off));
        mxv = fmaxf(mxv, __shfl_down(mxv, off));
    }
    if ((t & 63) == 0) { rmn[t >> 6] = mnv; rmx[t >> 6] = mxv; }
    __syncthreads();
    if (t == 0) {
        for (int w2 = 1; w2 < 8; w2++) { mnv = fminf(mnv, rmn[w2]); mxv = fmaxf(mxv, rmx[w2]); }
        atomicMin(&mnmx[seg], enc_f(mnv));
        atomicMax(&mnmx[4 + seg], enc_f(mxv));
    }
}

// ---------------- final fc1(gelu) + fc2: same 2-tile scalar-weight structure ----------------
__global__ __launch_bounds__(512, 4) void k_fc12(
    const float* __restrict__ hglob, const float* __restrict__ f1w,
    const float* __restrict__ f1b, const float* __restrict__ f2w,
    const float* __restrict__ f2b, float* __restrict__ out) {
    __shared__ float hx[128 * 128];
    int bid = blockIdx.x;                  // 512 blocks
    int b = bid >> 6;
    int l0 = (bid & 63) * 128;
    int t = threadIdx.x;
    const float* hb = hglob + (long)b * 1048576;
    #pragma unroll
    for (int i = 0; i < 8; i++) {
        int idx = t + i * 512;
        int row = idx >> 5, c4 = (idx & 31) * 4;
        *(float4*)&hx[row * 128 + c4] = *(const float4*)&hb[(long)row * 8192 + l0 + c4];
    }
    __syncthreads();
    int p = t & 63;
    int h0 = __builtin_amdgcn_readfirstlane((t >> 6) * 16);
    float acc0[16] = {}, acc1[16] = {};
    const float* f1 = f1w + h0;
    #pragma unroll 4
    for (int j = 0; j < 128; j++) {
        float xv0 = hx[j * 128 + p];
        float xv1 = hx[j * 128 + 64 + p];
        #pragma unroll
        for (int c = 0; c < 16; c++) {
            float wv = f1[j * 128 + c];
            acc0[c] = fmaf(wv, xv0, acc0[c]);
            acc1[c] = fmaf(wv, xv1, acc1[c]);
        }
    }
    float outp0 = 0.0f, outp1 = 0.0f;
    #pragma unroll
    for (int c = 0; c < 16; c++) {
        float bias = f1b[h0 + c];
        float fw = f2w[h0 + c];
        outp0 = fmaf(fw, gelu_f(acc0[c] + bias), outp0);
        outp1 = fmaf(fw, gelu_f(acc1[c] + bias), outp1);
    }
    __syncthreads();   // done reading hx; reuse as wave-partial buffer [8][128]
    hx[(t >> 6) * 128 + p] = outp0;
    hx[(t >> 6) * 128 + 64 + p] = outp1;
    __syncthreads();
    if (t < 128) {
        float s = f2b[0];
        #pragma unroll
        for (int gg = 0; gg < 8; gg++) s += hx[gg * 128 + t];
        out[(long)b * 8192 + l0 + t] = s;
    }
}

extern "C" void kernel_launch(void* const* d_in, const int* in_sizes, int n_in,
                              void* d_out, int out_size, void* d_ws, size_t ws_size,
                              hipStream_t stream) {
    const float* x     = (const float*)d_in[0];
    const float* fc0_w = (const float*)d_in[1];
    const float* fc0_b = (const float*)d_in[2];
    const float* swr   = (const float*)d_in[3];
    const float* swi   = (const float*)d_in[4];
    const float* cw    = (const float*)d_in[5];
    const float* cb    = (const float*)d_in[6];
    const float* chw   = (const float*)d_in[7];
    const float* gw    = (const float*)d_in[8];
    const float* gb    = (const float*)d_in[9];
    const float* f1w   = (const float*)d_in[10];
    const float* f1b   = (const float*)d_in[11];
    const float* f2w   = (const float*)d_in[12];
    const float* f2b   = (const float*)d_in[13];
    float* ws = (float*)d_ws;
    float* out = (float*)d_out;

    k_tab<<<32, 256, 0, stream>>>(ws);
    k_init2<<<2112, 256, 0, stream>>>(ws, chw);
    k_fc0<<<256, 256, 0, stream>>>(ws, x, fc0_w, fc0_b);
    for (int layer = 0; layer < 4; layer++) {
        k_dftcb<<<1024, 256, 0, stream>>>(ws, layer);
        k_b2<<<144, 256, 0, stream>>>(ws, swr, swi, gw, gb, layer);
        k_fuse<<<512, 512, 0, stream>>>(ws + OFF_H, ws + OFF_BASTC, ws + OFF_BASTS,
                                        ws + OFF_OMCT, ws + OFF_OMST, ws + OFF_REC,
                                        ws + OFF_CG, (unsigned int*)(ws + OFF_MNMX),
                                        cw, cb, gw, layer);
    }
    k_fc12<<<512, 512, 0, stream>>>(ws + OFF_H, f1w, f1b, f2w, f2b, out);
}